// Round 5
// baseline (166.969 us; speedup 1.0000x reference)
//
#include <hip/hip_runtime.h>
#include <math.h>

// inputs/targets [32, 8, 256, 256] fp32; softmax over dim 1 (C=8).
constexpr int HW_ = 256 * 256;               // 65536
constexpr float FEPS = 1e-6f;
constexpr float NUM_COLS = 8.0f * 65536.0f;  // 524288

// Grid: 256 blocks x 512 threads (1 block/CU, 8 waves/CU).
// Lane owns 4 consecutive hw (float4 loads: 16 B/lane, 1 KB/wave-instr).
// Wave w handles batches 4w..4w+3; block covers all 32 batches x 256 hw.
__global__ __launch_bounds__(512, 2) void dice_main(const float* __restrict__ in,
                                                    const float* __restrict__ tg,
                                                    float* __restrict__ accum,
                                                    unsigned int* __restrict__ counter,
                                                    float* __restrict__ out) {
    const int tid  = threadIdx.x;
    const int lane = tid & 63;
    const int w    = tid >> 6;                 // wave id 0..7
    const int hw0  = blockIdx.x * 256 + lane * 4;

    float inter[4][8], den[4][8];
#pragma unroll
    for (int v = 0; v < 4; ++v)
#pragma unroll
        for (int c = 0; c < 8; ++c) { inter[v][c] = 0.0f; den[v][c] = 0.0f; }

#pragma unroll
    for (int bi = 0; bi < 4; ++bi) {
        const int b    = w * 4 + bi;
        const int base = b * 8 * HW_ + hw0;    // < 2^24, int math safe

        // All 16 float4 loads (8 in + 8 tg) issued before any compute:
        // 16 KB in flight per wave-iter, 16 B/lane per instr.
        float4 xv[8], tv[8];
#pragma unroll
        for (int c = 0; c < 8; ++c) {
            xv[c] = *reinterpret_cast<const float4*>(in + base + c * HW_);
            tv[c] = *reinterpret_cast<const float4*>(tg + base + c * HW_);
        }

        float m[4];
        m[0] = xv[0].x; m[1] = xv[0].y; m[2] = xv[0].z; m[3] = xv[0].w;
#pragma unroll
        for (int c = 1; c < 8; ++c) {
            m[0] = fmaxf(m[0], xv[c].x); m[1] = fmaxf(m[1], xv[c].y);
            m[2] = fmaxf(m[2], xv[c].z); m[3] = fmaxf(m[3], xv[c].w);
        }

        float e[4][8], s[4] = {0.f, 0.f, 0.f, 0.f};
#pragma unroll
        for (int c = 0; c < 8; ++c) {
            e[0][c] = __expf(xv[c].x - m[0]); s[0] += e[0][c];
            e[1][c] = __expf(xv[c].y - m[1]); s[1] += e[1][c];
            e[2][c] = __expf(xv[c].z - m[2]); s[2] += e[2][c];
            e[3][c] = __expf(xv[c].w - m[3]); s[3] += e[3][c];
        }
        float r[4];
#pragma unroll
        for (int v = 0; v < 4; ++v) r[v] = 1.0f / s[v];

#pragma unroll
        for (int c = 0; c < 8; ++c) {
            const float t0 = tv[c].x, t1 = tv[c].y, t2 = tv[c].z, t3 = tv[c].w;
            const float p0 = e[0][c] * r[0];
            const float p1 = e[1][c] * r[1];
            const float p2 = e[2][c] * r[2];
            const float p3 = e[3][c] * r[3];
            inter[0][c] = fmaf(p0, t0, inter[0][c]); den[0][c] += p0 + t0;
            inter[1][c] = fmaf(p1, t1, inter[1][c]); den[1][c] += p1 + t1;
            inter[2][c] = fmaf(p2, t2, inter[2][c]); den[2][c] += p2 + t2;
            inter[3][c] = fmaf(p3, t3, inter[3][c]); den[3][c] += p3 + t3;
        }
    }

    // Cross-wave (batch-group) reduction: LDS tree, stride 65 (odd) ->
    // lane*65 mod 32 = lane -> conflict-free writes. 8*64*65*4 = 133 KB,
    // 1 block/CU (grid == 256) so LDS fits.
    __shared__ float red[8][64][65];
#pragma unroll
    for (int v = 0; v < 4; ++v)
#pragma unroll
        for (int c = 0; c < 8; ++c) {
            red[w][lane][v * 8 + c]      = inter[v][c];
            red[w][lane][32 + v * 8 + c] = den[v][c];
        }
    __syncthreads();

    // 2048 columns per block (256 hw x 8 c); 512 threads finish 4 each.
    float part = 0.0f;
#pragma unroll
    for (int i = 0; i < 4; ++i) {
        const int j    = tid * 4 + i;      // 0..2047
        const int hw_l = j >> 3;           // 0..255
        const int c    = j & 7;
        const int ln   = hw_l >> 2;
        const int v    = hw_l & 3;
        float I = 0.0f, D = 0.0f;
#pragma unroll
        for (int ww = 0; ww < 8; ++ww) {
            I += red[ww][ln][v * 8 + c];
            D += red[ww][ln][32 + v * 8 + c];
        }
        part += (2.0f * I + FEPS) / (D + FEPS);
    }

#pragma unroll
    for (int off = 32; off > 0; off >>= 1) part += __shfl_down(part, off, 64);

    __shared__ float wsum[8];
    if (lane == 0) wsum[w] = part;
    __syncthreads();

    if (tid == 0) {
        float bs = 0.0f;
#pragma unroll
        for (int ww = 0; ww < 8; ++ww) bs += wsum[ww];
        atomicAdd(accum, bs);
        __threadfence();                              // device-scope publish
        const unsigned int done = atomicAdd(counter, 1u);
        if (done == gridDim.x - 1) {                  // last block finalizes
            const float tot = atomicAdd(accum, 0.0f); // atomic read-back
            out[0] = 1.0f - tot * (1.0f / NUM_COLS);
        }
    }
}

extern "C" void kernel_launch(void* const* d_in, const int* in_sizes, int n_in,
                              void* d_out, int out_size, void* d_ws, size_t ws_size,
                              hipStream_t stream) {
    const float* in = (const float*)d_in[0];
    const float* tg = (const float*)d_in[1];
    float* out = (float*)d_out;
    float* accum = (float*)d_ws;                       // ws[0]: float accum
    unsigned int* counter = (unsigned int*)d_ws + 1;   // ws[1]: block counter

    // d_ws is re-poisoned to 0xAA before every timed launch -> zero both words.
    hipMemsetAsync(d_ws, 0, 8, stream);
    dice_main<<<dim3(HW_ / 256), dim3(512), 0, stream>>>(in, tg, accum, counter, out);
}

// Round 6
// 163.762 us; speedup vs baseline: 1.0196x; 1.0196x over previous
//
#include <hip/hip_runtime.h>
#include <math.h>

// inputs/targets [32, 8, 256, 256] fp32; softmax over dim 1 (C=8).
constexpr int HW_ = 256 * 256;               // 65536
constexpr float FEPS = 1e-6f;
constexpr float NUM_COLS = 8.0f * 65536.0f;  // 524288

// Grid: 512 blocks x 512 threads, 8 waves/block, all 32 batches per block.
// Wave w handles batches 4w..4w+3; lane owns 2 hw (float2, 512B/wave-instr).
// Target: 16 waves/CU (needs <=128 VGPR, achieved structurally: no e[] array,
// batch loop not unrolled, NO min-waves launch_bounds arg — that arg caused
// spills in R3/R4/R5).
__global__ __launch_bounds__(512) void dice_main(const float* __restrict__ in,
                                                 const float* __restrict__ tg,
                                                 float* __restrict__ accum,
                                                 unsigned int* __restrict__ counter,
                                                 float* __restrict__ out) {
    const int tid  = threadIdx.x;
    const int lane = tid & 63;
    const int w    = tid >> 6;                 // wave id 0..7
    const int hw0  = blockIdx.x * 128 + lane * 2;

    float inter[2][8], den[2][8];
#pragma unroll
    for (int v = 0; v < 2; ++v)
#pragma unroll
        for (int c = 0; c < 8; ++c) { inter[v][c] = 0.0f; den[v][c] = 0.0f; }

#pragma unroll 1   // keep register pressure flat across batch iterations
    for (int bi = 0; bi < 4; ++bi) {
        const int b    = w * 4 + bi;
        const int base = b * 8 * HW_ + hw0;    // < 2^24, int math safe

        // All 16 loads (8 in + 8 tg) issued before any compute.
        float2 xv[8], tv[8];
#pragma unroll
        for (int c = 0; c < 8; ++c) {
            xv[c] = *reinterpret_cast<const float2*>(in + base + c * HW_);
            tv[c] = *reinterpret_cast<const float2*>(tg + base + c * HW_);
        }

        float m0 = xv[0].x, m1 = xv[0].y;
#pragma unroll
        for (int c = 1; c < 8; ++c) { m0 = fmaxf(m0, xv[c].x); m1 = fmaxf(m1, xv[c].y); }

        float s0 = 0.0f, s1 = 0.0f;
#pragma unroll
        for (int c = 0; c < 8; ++c) {
            s0 += __expf(xv[c].x - m0);
            s1 += __expf(xv[c].y - m1);
        }
        const float r0 = 1.0f / s0;
        const float r1 = 1.0f / s1;

        // Recompute exp here instead of keeping e[2][8] live (-16 VGPR).
#pragma unroll
        for (int c = 0; c < 8; ++c) {
            const float p0 = __expf(xv[c].x - m0) * r0;
            const float p1 = __expf(xv[c].y - m1) * r1;
            inter[0][c] = fmaf(p0, tv[c].x, inter[0][c]);
            inter[1][c] = fmaf(p1, tv[c].y, inter[1][c]);
            den[0][c] += p0 + tv[c].x;
            den[1][c] += p1 + tv[c].y;
        }
    }

    // Cross-wave (batch-group) reduction: 8 partial sets, LDS tree.
    // [8][64][33]: stride 33 (odd) -> lane*33 mod 32 = lane -> conflict-free.
    // 67.6 KB; 2 blocks/CU -> 135 KB of 160 KB, fits.
    __shared__ float red[8][64][33];
#pragma unroll
    for (int v = 0; v < 2; ++v)
#pragma unroll
        for (int c = 0; c < 8; ++c) {
            red[w][lane][v * 8 + c]      = inter[v][c];
            red[w][lane][16 + v * 8 + c] = den[v][c];
        }
    __syncthreads();

    // 1024 columns per block (128 hw x 8 c); 512 threads finish 2 each.
    float part = 0.0f;
#pragma unroll
    for (int i = 0; i < 2; ++i) {
        const int j    = tid * 2 + i;      // 0..1023
        const int hw_l = j >> 3;           // 0..127
        const int c    = j & 7;
        const int ln   = hw_l >> 1;
        const int v    = hw_l & 1;
        float I = 0.0f, D = 0.0f;
#pragma unroll
        for (int ww = 0; ww < 8; ++ww) {
            I += red[ww][ln][v * 8 + c];
            D += red[ww][ln][16 + v * 8 + c];
        }
        part += (2.0f * I + FEPS) / (D + FEPS);
    }

#pragma unroll
    for (int off = 32; off > 0; off >>= 1) part += __shfl_down(part, off, 64);

    __shared__ float wsum[8];
    if (lane == 0) wsum[w] = part;
    __syncthreads();

    if (tid == 0) {
        float bs = 0.0f;
#pragma unroll
        for (int ww = 0; ww < 8; ++ww) bs += wsum[ww];
        atomicAdd(accum, bs);
        __threadfence();                              // device-scope publish
        const unsigned int done = atomicAdd(counter, 1u);
        if (done == gridDim.x - 1) {                  // last block finalizes
            const float tot = atomicAdd(accum, 0.0f); // atomic read-back
            out[0] = 1.0f - tot * (1.0f / NUM_COLS);
        }
    }
}

extern "C" void kernel_launch(void* const* d_in, const int* in_sizes, int n_in,
                              void* d_out, int out_size, void* d_ws, size_t ws_size,
                              hipStream_t stream) {
    const float* in = (const float*)d_in[0];
    const float* tg = (const float*)d_in[1];
    float* out = (float*)d_out;
    float* accum = (float*)d_ws;                       // ws[0]: float accum
    unsigned int* counter = (unsigned int*)d_ws + 1;   // ws[1]: block counter

    // d_ws is re-poisoned to 0xAA before every timed launch -> zero both words.
    hipMemsetAsync(d_ws, 0, 8, stream);
    dice_main<<<dim3(HW_ / 128), dim3(512), 0, stream>>>(in, tg, accum, counter, out);
}

// Round 9
// 152.449 us; speedup vs baseline: 1.0952x; 1.0742x over previous
//
#include <hip/hip_runtime.h>
#include <math.h>

// inputs/targets [32, 8, 256, 256] fp32; softmax over dim 1 (C=8).
constexpr int HW_ = 256 * 256;               // 65536
constexpr float FEPS = 1e-6f;
constexpr float NUM_COLS = 8.0f * 65536.0f;  // 524288

// Grid: 256 blocks x 512 threads (1 block/CU, 8 waves/CU).
// Lane owns 4 hw (float4 = 16 B/lane — bytes-per-load-instruction is the
// lever: per-CU outstanding-miss INSTRUCTION slots are the bottleneck, so
// double the bytes per slot). Wave w owns batches 4w..4w+3.
// Register diet (R6 lessons): no e[] array (recompute exp), batch loop NOT
// unrolled, and NO min-waves launch_bounds arg (it caused spills in R3-R5).
__global__ __launch_bounds__(512) void dice_main(const float* __restrict__ in,
                                                 const float* __restrict__ tg,
                                                 float* __restrict__ accum,
                                                 unsigned int* __restrict__ counter,
                                                 float* __restrict__ out) {
    const int tid  = threadIdx.x;
    const int lane = tid & 63;
    const int w    = tid >> 6;                 // wave id 0..7
    const int hw0  = blockIdx.x * 256 + lane * 4;

    float inter[4][8], den[4][8];
#pragma unroll
    for (int v = 0; v < 4; ++v)
#pragma unroll
        for (int c = 0; c < 8; ++c) { inter[v][c] = 0.0f; den[v][c] = 0.0f; }

#pragma unroll 1   // keep register pressure flat across batch iterations
    for (int bi = 0; bi < 4; ++bi) {
        const int b    = w * 4 + bi;
        const int base = b * 8 * HW_ + hw0;    // < 2^24, int math safe

        // All 16 float4 loads (8 in + 8 tg) issued before any compute.
        float4 xv[8], tv[8];
#pragma unroll
        for (int c = 0; c < 8; ++c) {
            xv[c] = *reinterpret_cast<const float4*>(in + base + c * HW_);
            tv[c] = *reinterpret_cast<const float4*>(tg + base + c * HW_);
        }

        float m0 = xv[0].x, m1 = xv[0].y, m2 = xv[0].z, m3 = xv[0].w;
#pragma unroll
        for (int c = 1; c < 8; ++c) {
            m0 = fmaxf(m0, xv[c].x); m1 = fmaxf(m1, xv[c].y);
            m2 = fmaxf(m2, xv[c].z); m3 = fmaxf(m3, xv[c].w);
        }

        float s0 = 0.f, s1 = 0.f, s2 = 0.f, s3 = 0.f;
#pragma unroll
        for (int c = 0; c < 8; ++c) {
            s0 += __expf(xv[c].x - m0);
            s1 += __expf(xv[c].y - m1);
            s2 += __expf(xv[c].z - m2);
            s3 += __expf(xv[c].w - m3);
        }
        const float r0 = 1.0f / s0, r1 = 1.0f / s1;
        const float r2 = 1.0f / s2, r3 = 1.0f / s3;

        // Recompute exp (VALU is ~9% busy — trade flops for 32 VGPRs).
#pragma unroll
        for (int c = 0; c < 8; ++c) {
            const float p0 = __expf(xv[c].x - m0) * r0;
            const float p1 = __expf(xv[c].y - m1) * r1;
            const float p2 = __expf(xv[c].z - m2) * r2;
            const float p3 = __expf(xv[c].w - m3) * r3;
            inter[0][c] = fmaf(p0, tv[c].x, inter[0][c]); den[0][c] += p0 + tv[c].x;
            inter[1][c] = fmaf(p1, tv[c].y, inter[1][c]); den[1][c] += p1 + tv[c].y;
            inter[2][c] = fmaf(p2, tv[c].z, inter[2][c]); den[2][c] += p2 + tv[c].z;
            inter[3][c] = fmaf(p3, tv[c].w, inter[3][c]); den[3][c] += p3 + tv[c].w;
        }
    }

    // Cross-wave (batch-group) reduction: LDS tree, stride 65 (odd) ->
    // lane*65 mod 32 = lane -> conflict-free writes. 8*64*65*4 = 133 KB,
    // grid = 256 -> 1 block/CU, fits.
    __shared__ float red[8][64][65];
#pragma unroll
    for (int v = 0; v < 4; ++v)
#pragma unroll
        for (int c = 0; c < 8; ++c) {
            red[w][lane][v * 8 + c]      = inter[v][c];
            red[w][lane][32 + v * 8 + c] = den[v][c];
        }
    __syncthreads();

    // 2048 columns per block (256 hw x 8 c); 512 threads finish 4 each.
    float part = 0.0f;
#pragma unroll
    for (int i = 0; i < 4; ++i) {
        const int j    = tid * 4 + i;      // 0..2047
        const int hw_l = j >> 3;           // 0..255
        const int c    = j & 7;
        const int ln   = hw_l >> 2;
        const int v    = hw_l & 3;
        float I = 0.0f, D = 0.0f;
#pragma unroll
        for (int ww = 0; ww < 8; ++ww) {
            I += red[ww][ln][v * 8 + c];
            D += red[ww][ln][32 + v * 8 + c];
        }
        part += (2.0f * I + FEPS) / (D + FEPS);
    }

#pragma unroll
    for (int off = 32; off > 0; off >>= 1) part += __shfl_down(part, off, 64);

    __shared__ float wsum[8];
    if (lane == 0) wsum[w] = part;
    __syncthreads();

    if (tid == 0) {
        float bs = 0.0f;
#pragma unroll
        for (int ww = 0; ww < 8; ++ww) bs += wsum[ww];
        atomicAdd(accum, bs);
        __threadfence();                              // device-scope publish
        const unsigned int done = atomicAdd(counter, 1u);
        if (done == gridDim.x - 1) {                  // last block finalizes
            const float tot = atomicAdd(accum, 0.0f); // atomic read-back
            out[0] = 1.0f - tot * (1.0f / NUM_COLS);
        }
    }
}

extern "C" void kernel_launch(void* const* d_in, const int* in_sizes, int n_in,
                              void* d_out, int out_size, void* d_ws, size_t ws_size,
                              hipStream_t stream) {
    const float* in = (const float*)d_in[0];
    const float* tg = (const float*)d_in[1];
    float* out = (float*)d_out;
    float* accum = (float*)d_ws;                       // ws[0]: float accum
    unsigned int* counter = (unsigned int*)d_ws + 1;   // ws[1]: block counter

    // d_ws is re-poisoned to 0xAA before every timed launch -> zero both words.
    hipMemsetAsync(d_ws, 0, 8, stream);
    dice_main<<<dim3(HW_ / 256), dim3(512), 0, stream>>>(in, tg, accum, counter, out);
}